// Round 1
// baseline (2057.274 us; speedup 1.0000x reference)
//
#include <hip/hip_runtime.h>

#define N_NODES   100000
#define N_EDGES   800000
#define N_ETYPES  5
#define IN_DIM    23
#define HID_DIM   128
#define OUT_DIM   64
#define NUM_GRAPHS 64

// ---------------- degree count / inverse ----------------
__global__ __launch_bounds__(256) void count_deg_k(const int* __restrict__ dst,
                                                   float* __restrict__ deg) {
    int e = blockIdx.y;
    int i = blockIdx.x * 256 + threadIdx.x;
    if (i < N_EDGES) {
        int d = dst[e * N_EDGES + i];
        atomicAdd(&deg[e * N_NODES + d], 1.0f);
    }
}

__global__ __launch_bounds__(256) void inv_deg_k(float* __restrict__ deg) {
    int i = blockIdx.x * 256 + threadIdx.x;
    if (i < N_ETYPES * N_NODES) deg[i] = 1.0f / (deg[i] + 1.0f);
}

// ---------------- layer1 edge scatter (23-dim, pre-scaled by inv[dst]) ------
// block = 256 threads = 8 edges x 32 lanes (23 active)
__global__ __launch_bounds__(256) void scatter1_k(const int* __restrict__ src,
                                                  const int* __restrict__ dst,
                                                  const float* __restrict__ feat,
                                                  const float* __restrict__ inv,
                                                  float* __restrict__ agg1) {
    int e = blockIdx.y;
    int lane = threadIdx.x & 31;
    int eidx = blockIdx.x * 8 + (threadIdx.x >> 5);
    if (eidx >= N_EDGES || lane >= IN_DIM) return;
    int s = src[e * N_EDGES + eidx];
    int d = dst[e * N_EDGES + eidx];
    float w = inv[e * N_NODES + d];
    atomicAdd(&agg1[(e * N_NODES + d) * IN_DIM + lane], feat[s * IN_DIM + lane] * w);
}

// ---------------- layer1 GEMM: h1 = relu(sum_e (agg1_e + feat*inv_e) @ W1[e] + B1)
// block 256, tile 128 nodes x 128 dims; thread = 4 nodes x 16 dims; loops all etypes.
__global__ __launch_bounds__(256) void gemm1_k(const float* __restrict__ feat,
                                               const float* __restrict__ agg1,
                                               const float* __restrict__ inv,
                                               const float* __restrict__ W1,
                                               const float* __restrict__ b1,
                                               float* __restrict__ h1) {
    __shared__ float xs[128 * 25];            // 128 nodes x 23 (pad to 25: conflict-free)
    __shared__ float wl[IN_DIM * HID_DIM];    // 23 x 128
    int t = threadIdx.x;
    int node0 = blockIdx.x * 128;
    int ng = t >> 3;   // 0..31 -> nodes 4*ng..4*ng+3
    int o  = t & 7;    // 0..7  -> dims 16*o..16*o+15
    float acc[4][16];
    for (int i = 0; i < 4; i++)
        for (int j = 0; j < 16; j++) acc[i][j] = 0.f;

    for (int e = 0; e < N_ETYPES; e++) {
        __syncthreads();
        for (int j = t; j < IN_DIM * HID_DIM; j += 256)
            wl[j] = W1[e * IN_DIM * HID_DIM + j];
        for (int j = t; j < 128 * IN_DIM; j += 256) {
            int nl = j / IN_DIM;
            int k  = j - nl * IN_DIM;
            int gn = node0 + nl;
            int cn = gn < N_NODES ? gn : N_NODES - 1;
            xs[nl * 25 + k] = agg1[(e * N_NODES + cn) * IN_DIM + k]
                            + feat[cn * IN_DIM + k] * inv[e * N_NODES + cn];
        }
        __syncthreads();
        // bias (once per node per etype)
        for (int j = 0; j < 16; j++) {
            float bb = b1[e * HID_DIM + o * 16 + j];
            for (int i = 0; i < 4; i++) acc[i][j] += bb;
        }
        for (int k = 0; k < IN_DIM; k++) {
            float xv[4];
            for (int i = 0; i < 4; i++) xv[i] = xs[(ng * 4 + i) * 25 + k];
            for (int j4 = 0; j4 < 4; j4++) {
                float4 w = *(const float4*)&wl[k * HID_DIM + o * 16 + j4 * 4];
                for (int i = 0; i < 4; i++) {
                    acc[i][j4 * 4 + 0] += xv[i] * w.x;
                    acc[i][j4 * 4 + 1] += xv[i] * w.y;
                    acc[i][j4 * 4 + 2] += xv[i] * w.z;
                    acc[i][j4 * 4 + 3] += xv[i] * w.w;
                }
            }
        }
    }
    for (int i = 0; i < 4; i++) {
        int gn = node0 + ng * 4 + i;
        if (gn < N_NODES) {
            for (int j4 = 0; j4 < 4; j4++) {
                float4 v;
                v.x = fmaxf(acc[i][j4 * 4 + 0], 0.f);
                v.y = fmaxf(acc[i][j4 * 4 + 1], 0.f);
                v.z = fmaxf(acc[i][j4 * 4 + 2], 0.f);
                v.w = fmaxf(acc[i][j4 * 4 + 3], 0.f);
                *(float4*)&h1[gn * HID_DIM + o * 16 + j4 * 4] = v;
            }
        }
    }
}

// ---------------- layer2 transform GEMM: t2 = h1 @ W2[e]; acc2 += t2*inv (self term)
// block 256, tile 256 nodes x 64 dims; thread = 4 nodes x 16 dims; K in 4 chunks of 32.
__global__ __launch_bounds__(256) void gemm2_k(const float* __restrict__ h1,
                                               const float* __restrict__ W2,
                                               const float* __restrict__ inv,
                                               float* __restrict__ t2,
                                               float* __restrict__ acc2, int e) {
    __shared__ float xs[256 * 33];          // 256 nodes x 32 k (pad 33)
    __shared__ float wl[32 * OUT_DIM];      // 32 k x 64 dims
    int t = threadIdx.x;
    int node0 = blockIdx.x * 256;
    int ng = t >> 2;   // 0..63 -> nodes 4*ng..4*ng+3
    int q  = t & 3;    // 0..3  -> dims 16*q..16*q+15
    float acc[4][16];
    for (int i = 0; i < 4; i++)
        for (int j = 0; j < 16; j++) acc[i][j] = 0.f;

    for (int kc = 0; kc < 4; kc++) {
        __syncthreads();
        int k0 = kc * 32;
        for (int j = t; j < 32 * OUT_DIM; j += 256)
            wl[j] = W2[e * HID_DIM * OUT_DIM + k0 * OUT_DIM + j];
        for (int j = t; j < 256 * 32; j += 256) {
            int nl = j >> 5;
            int kk = j & 31;
            int gn = node0 + nl;
            int cn = gn < N_NODES ? gn : N_NODES - 1;
            xs[nl * 33 + kk] = h1[cn * HID_DIM + k0 + kk];
        }
        __syncthreads();
        for (int kk = 0; kk < 32; kk++) {
            float xv[4];
            for (int i = 0; i < 4; i++) xv[i] = xs[(ng * 4 + i) * 33 + kk];
            for (int j4 = 0; j4 < 4; j4++) {
                float4 w = *(const float4*)&wl[kk * OUT_DIM + q * 16 + j4 * 4];
                for (int i = 0; i < 4; i++) {
                    acc[i][j4 * 4 + 0] += xv[i] * w.x;
                    acc[i][j4 * 4 + 1] += xv[i] * w.y;
                    acc[i][j4 * 4 + 2] += xv[i] * w.z;
                    acc[i][j4 * 4 + 3] += xv[i] * w.w;
                }
            }
        }
    }
    for (int i = 0; i < 4; i++) {
        int gn = node0 + ng * 4 + i;
        if (gn < N_NODES) {
            float iv = inv[e * N_NODES + gn];
            for (int j4 = 0; j4 < 4; j4++) {
                int base = gn * OUT_DIM + q * 16 + j4 * 4;
                float4 v;
                v.x = acc[i][j4 * 4 + 0];
                v.y = acc[i][j4 * 4 + 1];
                v.z = acc[i][j4 * 4 + 2];
                v.w = acc[i][j4 * 4 + 3];
                *(float4*)&t2[base] = v;
                float4 a = *(float4*)&acc2[base];   // exclusive (i,d) per thread; stream-ordered
                a.x += v.x * iv; a.y += v.y * iv; a.z += v.z * iv; a.w += v.w * iv;
                *(float4*)&acc2[base] = a;
            }
        }
    }
}

// ---------------- layer2 edge scatter (64-dim, pre-scaled) ----------------
// block = 256 threads = 4 edges x 64 lanes
__global__ __launch_bounds__(256) void scatter2_k(const int* __restrict__ src,
                                                  const int* __restrict__ dst,
                                                  const float* __restrict__ t2,
                                                  const float* __restrict__ inv,
                                                  float* __restrict__ acc2, int e) {
    int lane = threadIdx.x & 63;
    int eidx = blockIdx.x * 4 + (threadIdx.x >> 6);
    if (eidx >= N_EDGES) return;
    int s = src[e * N_EDGES + eidx];
    int d = dst[e * N_EDGES + eidx];
    float w = inv[e * N_NODES + d];
    atomicAdd(&acc2[d * OUT_DIM + lane], t2[s * OUT_DIM + lane] * w);
}

// ---------------- per-graph mean pool (graph_ids sorted -> run-length flush) ----
__global__ __launch_bounds__(256) void pool_k(const float* __restrict__ acc2,
                                              const int* __restrict__ gid,
                                              float* __restrict__ gsum,
                                              float* __restrict__ gcnt) {
    int t = threadIdx.x;
    int d = t & 63;
    int r = t >> 6;                 // wave index 0..3 (wave-uniform control flow)
    int i0 = blockIdx.x * 256;
    float sum = 0.f, cnt = 0.f;
    int cur = -1;
    for (int i = i0 + r; i < i0 + 256 && i < N_NODES; i += 4) {
        int g = gid[i];
        if (g != cur) {
            if (cur >= 0) {
                atomicAdd(&gsum[cur * 64 + d], sum);
                if (d == 0) atomicAdd(&gcnt[cur], cnt);
            }
            cur = g; sum = 0.f; cnt = 0.f;
        }
        sum += acc2[i * 64 + d];
        cnt += 1.f;
    }
    if (cur >= 0) {
        atomicAdd(&gsum[cur * 64 + d], sum);
        if (d == 0) atomicAdd(&gcnt[cur], cnt);
    }
}

__global__ __launch_bounds__(256) void final_k(const float* __restrict__ gsum,
                                               const float* __restrict__ gcnt,
                                               const float* __restrict__ b2,
                                               float* __restrict__ out) {
    int idx = blockIdx.x * 256 + threadIdx.x;
    if (idx >= NUM_GRAPHS * OUT_DIM) return;
    int d = idx & 63;
    float B2 = 0.f;
    for (int e = 0; e < N_ETYPES; e++) B2 += b2[e * OUT_DIM + d];
    float c = gcnt[idx >> 6];
    out[idx] = (gsum[idx] + c * B2) / fmaxf(c, 1.0f);
}

extern "C" void kernel_launch(void* const* d_in, const int* in_sizes, int n_in,
                              void* d_out, int out_size, void* d_ws, size_t ws_size,
                              hipStream_t stream) {
    const float* feat = (const float*)d_in[0];
    const int*   src  = (const int*)d_in[1];
    const int*   dst  = (const int*)d_in[2];
    const int*   gid  = (const int*)d_in[3];
    const float* W1   = (const float*)d_in[4];
    const float* b1   = (const float*)d_in[5];
    const float* W2   = (const float*)d_in[6];
    const float* b2   = (const float*)d_in[7];

    float* ws   = (float*)d_ws;
    float* DEG  = ws;                 // 5*100000            = 500,000
    float* AGG1 = ws + 500000;        // 5*100000*23         = 11,500,000
    float* ACC2 = ws + 12000000;      // 100000*64           = 6,400,000
    float* GSUM = ws + 18400000;      // 64*64               = 4096
    float* GCNT = ws + 18404096;      // 64
    float* H1   = ws + 18404160;      // 100000*128          = 12,800,000
    float* T2   = ws + 31204160;      // 100000*64           = 6,400,000
    // total: 37,604,160 floats = 150.4 MB

    // zero the accumulated regions (ws is poisoned 0xAA before every call)
    hipMemsetAsync(DEG,  0, (size_t)12000000 * sizeof(float), stream);          // DEG+AGG1
    hipMemsetAsync(ACC2, 0, (size_t)(6400000 + 4096 + 64) * sizeof(float), stream); // ACC2+GSUM+GCNT

    count_deg_k<<<dim3(3125, N_ETYPES), 256, 0, stream>>>(dst, DEG);
    inv_deg_k<<<1954, 256, 0, stream>>>(DEG);
    scatter1_k<<<dim3(100000, N_ETYPES), 256, 0, stream>>>(src, dst, feat, DEG, AGG1);
    gemm1_k<<<782, 256, 0, stream>>>(feat, AGG1, DEG, W1, b1, H1);
    for (int e = 0; e < N_ETYPES; e++) {
        gemm2_k<<<391, 256, 0, stream>>>(H1, W2, DEG, T2, ACC2, e);
        scatter2_k<<<200000, 256, 0, stream>>>(src, dst, T2, DEG, ACC2, e);
    }
    pool_k<<<391, 256, 0, stream>>>(ACC2, gid, GSUM, GCNT);
    final_k<<<16, 256, 0, stream>>>(GSUM, GCNT, b2, (float*)d_out);
}

// Round 2
// 1288.049 us; speedup vs baseline: 1.5972x; 1.5972x over previous
//
#include <hip/hip_runtime.h>

#define N_NODES   100000
#define N_EDGES   800000
#define N_ETYPES  5
#define IN_DIM    23
#define HID_DIM   128
#define OUT_DIM   64
#define NUM_GRAPHS 64
#define N_EN      (N_ETYPES * N_NODES)   // 500000 flattened (etype,node)
#define SCAN_NBLK 489                    // ceil(500000/1024)

// ---------------- degree count (int atomics on 2 MB — cheap) ----------------
__global__ __launch_bounds__(256) void deg_count_k(const int* __restrict__ dst,
                                                   int* __restrict__ degi) {
    int e = blockIdx.y;
    int i = blockIdx.x * 256 + threadIdx.x;
    int d = dst[e * N_EDGES + i];
    atomicAdd(&degi[e * N_NODES + d], 1);
}

// ---------------- exclusive scan over 500k (3 kernels) ----------------
__global__ __launch_bounds__(256) void scan1_k(const int* __restrict__ degi,
                                               int* __restrict__ off,
                                               int* __restrict__ bsum) {
    __shared__ int ls[256];
    int t = threadIdx.x;
    int base = blockIdx.x * 1024 + t * 4;
    int v[4]; int s = 0;
    for (int j = 0; j < 4; j++) {
        int i = base + j;
        v[j] = (i < N_EN) ? degi[i] : 0;
        s += v[j];
    }
    ls[t] = s; __syncthreads();
    for (int o = 1; o < 256; o <<= 1) {
        int x = (t >= o) ? ls[t - o] : 0;
        __syncthreads();
        ls[t] += x;
        __syncthreads();
    }
    int excl = (t > 0) ? ls[t - 1] : 0;
    if (t == 255) bsum[blockIdx.x] = ls[255];
    int run = excl;
    for (int j = 0; j < 4; j++) {
        int i = base + j;
        if (i < N_EN) off[i] = run;
        run += v[j];
    }
}

__global__ __launch_bounds__(512) void scan2_k(int* __restrict__ bsum) {
    __shared__ int ls[512];
    int t = threadIdx.x;
    int v = (t < SCAN_NBLK) ? bsum[t] : 0;
    ls[t] = v; __syncthreads();
    for (int o = 1; o < 512; o <<= 1) {
        int x = (t >= o) ? ls[t - o] : 0;
        __syncthreads();
        ls[t] += x;
        __syncthreads();
    }
    int excl = (t > 0) ? ls[t - 1] : 0;
    if (t < SCAN_NBLK) bsum[t] = excl;
}

__global__ __launch_bounds__(256) void scan3_k(const int* __restrict__ degi,
                                               int* __restrict__ off,
                                               const int* __restrict__ bsum,
                                               int* __restrict__ cur,
                                               float* __restrict__ inv) {
    int i = blockIdx.x * 256 + threadIdx.x;
    if (i >= N_EN) return;
    int o = off[i] + bsum[i >> 10];
    off[i] = o;
    cur[i] = o;
    inv[i] = 1.0f / (float)(degi[i] + 1);
}

// ---------------- CSR fill (int atomics on cursor) ----------------
__global__ __launch_bounds__(256) void csr_fill_k(const int* __restrict__ src,
                                                  const int* __restrict__ dst,
                                                  int* __restrict__ cur,
                                                  int* __restrict__ csr) {
    int e = blockIdx.y;
    int i = blockIdx.x * 256 + threadIdx.x;
    int d = dst[e * N_EDGES + i];
    int s = src[e * N_EDGES + i];
    int pos = atomicAdd(&cur[e * N_NODES + d], 1);
    csr[pos] = s;
}

// ---------------- layer1 gather: AGG1[e,n,:] = inv * sum_{j->n} feat[j,:] ----
// 32 lanes per (e,node), 8 nodes per block
__global__ __launch_bounds__(256) void agg1_k(const int* __restrict__ off,
                                              const int* __restrict__ degi,
                                              const int* __restrict__ csr,
                                              const float* __restrict__ feat,
                                              const float* __restrict__ inv,
                                              float* __restrict__ agg1) {
    int e = blockIdx.y;
    int t = threadIdx.x;
    int lane = t & 31;
    int n = blockIdx.x * 8 + (t >> 5);
    int idx = e * N_NODES + n;
    int st = off[idx];
    int cnt = degi[idx];
    float a = 0.f;
    if (lane < IN_DIM) {
        int k = 0;
        for (; k + 1 < cnt; k += 2) {
            int s0 = csr[st + k];
            int s1 = csr[st + k + 1];
            a += feat[s0 * IN_DIM + lane];
            a += feat[s1 * IN_DIM + lane];
        }
        if (k < cnt) {
            int s0 = csr[st + k];
            a += feat[s0 * IN_DIM + lane];
        }
        agg1[idx * IN_DIM + lane] = a * inv[idx];
    }
}

// ---------------- layer1 GEMM: h1 = relu(sum_e (agg1_e + feat*inv_e) @ W1[e] + B1)
__global__ __launch_bounds__(256) void gemm1_k(const float* __restrict__ feat,
                                               const float* __restrict__ agg1,
                                               const float* __restrict__ inv,
                                               const float* __restrict__ W1,
                                               const float* __restrict__ b1,
                                               float* __restrict__ h1) {
    __shared__ float xs[128 * 25];
    __shared__ float wl[IN_DIM * HID_DIM];
    int t = threadIdx.x;
    int node0 = blockIdx.x * 128;
    int ng = t >> 3;
    int o  = t & 7;
    float acc[4][16];
    for (int i = 0; i < 4; i++)
        for (int j = 0; j < 16; j++) acc[i][j] = 0.f;

    for (int e = 0; e < N_ETYPES; e++) {
        __syncthreads();
        for (int j = t; j < IN_DIM * HID_DIM; j += 256)
            wl[j] = W1[e * IN_DIM * HID_DIM + j];
        for (int j = t; j < 128 * IN_DIM; j += 256) {
            int nl = j / IN_DIM;
            int k  = j - nl * IN_DIM;
            int gn = node0 + nl;
            int cn = gn < N_NODES ? gn : N_NODES - 1;
            xs[nl * 25 + k] = agg1[(e * N_NODES + cn) * IN_DIM + k]
                            + feat[cn * IN_DIM + k] * inv[e * N_NODES + cn];
        }
        __syncthreads();
        for (int j = 0; j < 16; j++) {
            float bb = b1[e * HID_DIM + o * 16 + j];
            for (int i = 0; i < 4; i++) acc[i][j] += bb;
        }
        for (int k = 0; k < IN_DIM; k++) {
            float xv[4];
            for (int i = 0; i < 4; i++) xv[i] = xs[(ng * 4 + i) * 25 + k];
            for (int j4 = 0; j4 < 4; j4++) {
                float4 w = *(const float4*)&wl[k * HID_DIM + o * 16 + j4 * 4];
                for (int i = 0; i < 4; i++) {
                    acc[i][j4 * 4 + 0] += xv[i] * w.x;
                    acc[i][j4 * 4 + 1] += xv[i] * w.y;
                    acc[i][j4 * 4 + 2] += xv[i] * w.z;
                    acc[i][j4 * 4 + 3] += xv[i] * w.w;
                }
            }
        }
    }
    for (int i = 0; i < 4; i++) {
        int gn = node0 + ng * 4 + i;
        if (gn < N_NODES) {
            for (int j4 = 0; j4 < 4; j4++) {
                float4 v;
                v.x = fmaxf(acc[i][j4 * 4 + 0], 0.f);
                v.y = fmaxf(acc[i][j4 * 4 + 1], 0.f);
                v.z = fmaxf(acc[i][j4 * 4 + 2], 0.f);
                v.w = fmaxf(acc[i][j4 * 4 + 3], 0.f);
                *(float4*)&h1[gn * HID_DIM + o * 16 + j4 * 4] = v;
            }
        }
    }
}

// ---------------- layer2 transform GEMM: t2 = h1 @ W2[e] ----------------
__global__ __launch_bounds__(256) void gemm2_k(const float* __restrict__ h1,
                                               const float* __restrict__ W2,
                                               float* __restrict__ t2, int e) {
    __shared__ float xs[256 * 33];
    __shared__ float wl[32 * OUT_DIM];
    int t = threadIdx.x;
    int node0 = blockIdx.x * 256;
    int ng = t >> 2;
    int q  = t & 3;
    float acc[4][16];
    for (int i = 0; i < 4; i++)
        for (int j = 0; j < 16; j++) acc[i][j] = 0.f;

    for (int kc = 0; kc < 4; kc++) {
        __syncthreads();
        int k0 = kc * 32;
        for (int j = t; j < 32 * OUT_DIM; j += 256)
            wl[j] = W2[e * HID_DIM * OUT_DIM + k0 * OUT_DIM + j];
        for (int j = t; j < 256 * 32; j += 256) {
            int nl = j >> 5;
            int kk = j & 31;
            int gn = node0 + nl;
            int cn = gn < N_NODES ? gn : N_NODES - 1;
            xs[nl * 33 + kk] = h1[cn * HID_DIM + k0 + kk];
        }
        __syncthreads();
        for (int kk = 0; kk < 32; kk++) {
            float xv[4];
            for (int i = 0; i < 4; i++) xv[i] = xs[(ng * 4 + i) * 33 + kk];
            for (int j4 = 0; j4 < 4; j4++) {
                float4 w = *(const float4*)&wl[kk * OUT_DIM + q * 16 + j4 * 4];
                for (int i = 0; i < 4; i++) {
                    acc[i][j4 * 4 + 0] += xv[i] * w.x;
                    acc[i][j4 * 4 + 1] += xv[i] * w.y;
                    acc[i][j4 * 4 + 2] += xv[i] * w.z;
                    acc[i][j4 * 4 + 3] += xv[i] * w.w;
                }
            }
        }
    }
    for (int i = 0; i < 4; i++) {
        int gn = node0 + ng * 4 + i;
        if (gn < N_NODES) {
            for (int j4 = 0; j4 < 4; j4++) {
                float4 v;
                v.x = acc[i][j4 * 4 + 0];
                v.y = acc[i][j4 * 4 + 1];
                v.z = acc[i][j4 * 4 + 2];
                v.w = acc[i][j4 * 4 + 3];
                *(float4*)&t2[gn * OUT_DIM + q * 16 + j4 * 4] = v;
            }
        }
    }
}

// ---------------- layer2 gather: acc2[n,:] += inv*(t2[n,:] + sum_{j->n} t2[j,:])
// 16 lanes (float4) per node, 16 nodes per block; exclusive RMW, no atomics
__global__ __launch_bounds__(256) void gather2_k(const int* __restrict__ off,
                                                 const int* __restrict__ degi,
                                                 const int* __restrict__ csr,
                                                 const float* __restrict__ t2,
                                                 const float* __restrict__ inv,
                                                 float* __restrict__ acc2, int e) {
    int t = threadIdx.x;
    int lane = t & 15;
    int n = blockIdx.x * 16 + (t >> 4);
    int idx = e * N_NODES + n;
    int st = off[idx];
    int cnt = degi[idx];
    const float4* t2v = (const float4*)t2;
    float4* accv = (float4*)acc2;
    float4 a = t2v[n * 16 + lane];          // self term
    int k = 0;
    for (; k + 1 < cnt; k += 2) {
        int s0 = csr[st + k];
        int s1 = csr[st + k + 1];
        float4 v0 = t2v[s0 * 16 + lane];
        float4 v1 = t2v[s1 * 16 + lane];
        a.x += v0.x + v1.x; a.y += v0.y + v1.y;
        a.z += v0.z + v1.z; a.w += v0.w + v1.w;
    }
    if (k < cnt) {
        int s0 = csr[st + k];
        float4 v0 = t2v[s0 * 16 + lane];
        a.x += v0.x; a.y += v0.y; a.z += v0.z; a.w += v0.w;
    }
    float iv = inv[idx];
    float4 o = accv[n * 16 + lane];
    o.x += a.x * iv; o.y += a.y * iv; o.z += a.z * iv; o.w += a.w * iv;
    accv[n * 16 + lane] = o;
}

// ---------------- per-graph mean pool ----------------
__global__ __launch_bounds__(256) void pool_k(const float* __restrict__ acc2,
                                              const int* __restrict__ gid,
                                              float* __restrict__ gsum,
                                              float* __restrict__ gcnt) {
    int t = threadIdx.x;
    int d = t & 63;
    int r = t >> 6;
    int i0 = blockIdx.x * 256;
    float sum = 0.f, cnt = 0.f;
    int cur = -1;
    for (int i = i0 + r; i < i0 + 256 && i < N_NODES; i += 4) {
        int g = gid[i];
        if (g != cur) {
            if (cur >= 0) {
                atomicAdd(&gsum[cur * 64 + d], sum);
                if (d == 0) atomicAdd(&gcnt[cur], cnt);
            }
            cur = g; sum = 0.f; cnt = 0.f;
        }
        sum += acc2[i * 64 + d];
        cnt += 1.f;
    }
    if (cur >= 0) {
        atomicAdd(&gsum[cur * 64 + d], sum);
        if (d == 0) atomicAdd(&gcnt[cur], cnt);
    }
}

__global__ __launch_bounds__(256) void final_k(const float* __restrict__ gsum,
                                               const float* __restrict__ gcnt,
                                               const float* __restrict__ b2,
                                               float* __restrict__ out) {
    int idx = blockIdx.x * 256 + threadIdx.x;
    if (idx >= NUM_GRAPHS * OUT_DIM) return;
    int d = idx & 63;
    float B2 = 0.f;
    for (int e = 0; e < N_ETYPES; e++) B2 += b2[e * OUT_DIM + d];
    float c = gcnt[idx >> 6];
    out[idx] = (gsum[idx] + c * B2) / fmaxf(c, 1.0f);
}

extern "C" void kernel_launch(void* const* d_in, const int* in_sizes, int n_in,
                              void* d_out, int out_size, void* d_ws, size_t ws_size,
                              hipStream_t stream) {
    const float* feat = (const float*)d_in[0];
    const int*   src  = (const int*)d_in[1];
    const int*   dst  = (const int*)d_in[2];
    const int*   gid  = (const int*)d_in[3];
    const float* W1   = (const float*)d_in[4];
    const float* b1   = (const float*)d_in[5];
    const float* W2   = (const float*)d_in[6];
    const float* b2   = (const float*)d_in[7];

    float* ws   = (float*)d_ws;
    int*   DEGI = (int*)ws;             // 500,000
    int*   OFF  = (int*)ws + 500000;    // 500,000
    int*   CUR  = (int*)ws + 1000000;   // 500,000
    int*   BSUM = (int*)ws + 1500000;   // 512
    float* INV  = ws + 1500512;         // 500,000
    int*   CSR  = (int*)ws + 2000512;   // 4,000,000
    float* AGG1 = ws + 6000512;         // 11,500,000
    float* T2   = AGG1;                 // 6,400,000 (aliases AGG1 — dead after gemm1)
    float* H1   = ws + 17500512;        // 12,800,000
    float* ACC2 = ws + 30300512;        // 6,400,000
    float* GSUM = ws + 36700512;        // 4,096
    float* GCNT = ws + 36704608;        // 64
    // total 36,704,672 floats = 146.8 MB

    hipMemsetAsync(DEGI, 0, (size_t)N_EN * sizeof(int), stream);
    hipMemsetAsync(ACC2, 0, (size_t)(6400000 + 4096 + 64) * sizeof(float), stream);

    deg_count_k<<<dim3(3125, N_ETYPES), 256, 0, stream>>>(dst, DEGI);
    scan1_k<<<SCAN_NBLK, 256, 0, stream>>>(DEGI, OFF, BSUM);
    scan2_k<<<1, 512, 0, stream>>>(BSUM);
    scan3_k<<<1954, 256, 0, stream>>>(DEGI, OFF, BSUM, CUR, INV);
    csr_fill_k<<<dim3(3125, N_ETYPES), 256, 0, stream>>>(src, dst, CUR, CSR);

    agg1_k<<<dim3(12500, N_ETYPES), 256, 0, stream>>>(OFF, DEGI, CSR, feat, INV, AGG1);
    gemm1_k<<<782, 256, 0, stream>>>(feat, AGG1, INV, W1, b1, H1);

    for (int e = 0; e < N_ETYPES; e++) {
        gemm2_k<<<391, 256, 0, stream>>>(H1, W2, T2, e);
        gather2_k<<<6250, 256, 0, stream>>>(OFF, DEGI, CSR, T2, INV, ACC2, e);
    }

    pool_k<<<391, 256, 0, stream>>>(ACC2, gid, GSUM, GCNT);
    final_k<<<16, 256, 0, stream>>>(GSUM, GCNT, b2, (float*)d_out);
}